// Round 1
// baseline (1337.904 us; speedup 1.0000x reference)
//
#include <hip/hip_runtime.h>
#include <math.h>

#define BATCH 8
#define SSIZE 1048576   // 128*128*64
#define KT 16

// ---------------- zero kernel (graph-capture-safe G clear) ----------------
__global__ void zero_kernel(float* __restrict__ p, int n) {
    int i = blockIdx.x * blockDim.x + threadIdx.x;
    if (i < n) p[i] = 0.0f;
}

// ---------------- Gram: G[b,i,j] = sum_k u(b,i,k)*u(b,j,k) (complex, no conj)
// u(b,i,k) addressed planar: off = b*SSIZE + i*SI + (k>>KL2)*SKH + (k&msk)*SKL
__global__ __launch_bounds__(256)
void gram_kernel(const float* __restrict__ srcR, const float* __restrict__ srcI,
                 float* __restrict__ G,
                 int d, int SI, int KL2, int SKL, int SKH, int kPerBlock)
{
    const int tilesJ = d >> 6;
    const int it = (blockIdx.x / tilesJ) << 6;
    const int jt = (blockIdx.x % tilesJ) << 6;
    const int b  = blockIdx.y;
    const int kbase0 = blockIdx.z * kPerBlock;
    const int msk = (1 << KL2) - 1;

    __shared__ float2 As[KT][66];   // [kk][i], pad 66 keeps 16B alignment for b128 reads
    __shared__ float2 Bs[KT][66];

    const int t  = threadIdx.x;
    const int ti = t & 15, tj = t >> 4;

    float accr[4][4] = {{0}}, acci[4][4] = {{0}};

    const size_t boff = (size_t)b * SSIZE;

    for (int kt = 0; kt < kPerBlock; kt += KT) {
        const int kb  = kbase0 + kt;
        const size_t koff = (size_t)(kb >> KL2) * SKH + (size_t)(kb & msk) * SKL;
        // load 64 i x 16 kk, both tiles; l: kk = l&15, ii = l>>4
        #pragma unroll
        for (int iter = 0; iter < 4; iter++) {
            int l  = iter * 256 + t;
            int kk = l & 15;
            int ii = l >> 4;
            size_t offA = boff + (size_t)(it + ii) * SI + koff + (size_t)kk * SKL;
            size_t offB = boff + (size_t)(jt + ii) * SI + koff + (size_t)kk * SKL;
            As[kk][ii] = make_float2(srcR[offA], srcI[offA]);
            Bs[kk][ii] = make_float2(srcR[offB], srcI[offB]);
        }
        __syncthreads();
        #pragma unroll
        for (int kk = 0; kk < KT; kk++) {
            float2 a[4], bb[4];
            #pragma unroll
            for (int r = 0; r < 4; r++) a[r]  = As[kk][ti * 4 + r];
            #pragma unroll
            for (int c = 0; c < 4; c++) bb[c] = Bs[kk][tj * 4 + c];
            #pragma unroll
            for (int r = 0; r < 4; r++)
                #pragma unroll
                for (int c = 0; c < 4; c++) {
                    accr[r][c] = fmaf(a[r].x,  bb[c].x, accr[r][c]);
                    accr[r][c] = fmaf(-a[r].y, bb[c].y, accr[r][c]);
                    acci[r][c] = fmaf(a[r].x,  bb[c].y, acci[r][c]);
                    acci[r][c] = fmaf(a[r].y,  bb[c].x, acci[r][c]);
                }
        }
        __syncthreads();
    }

    float* Gb = G + (size_t)b * d * d * 2;
    #pragma unroll
    for (int r = 0; r < 4; r++)
        #pragma unroll
        for (int c = 0; c < 4; c++) {
            int i = it + ti * 4 + r;
            int j = jt + tj * 4 + c;
            atomicAdd(&Gb[(i * d + j) * 2 + 0], accr[r][c]);
            atomicAdd(&Gb[(i * d + j) * 2 + 1], acci[r][c]);
        }
}

// ---------------- score/softmax/phase -> routing matrix M ----------------
// one block per (b,i); thread j computes score[i,j] = sum_l W[i,l]*G[b,l,j]
__global__ __launch_bounds__(128)
void score_kernel(const float* __restrict__ G,
                  const float* __restrict__ Wre, const float* __restrict__ Wim,
                  const float* __restrict__ log_tau,
                  float2* __restrict__ Mout, int d)
{
    const int b = blockIdx.y;
    const int i = blockIdx.x;
    const int j = threadIdx.x;     // 0..d-1 (blockDim == d)

    const float2* Gb = (const float2*)G + (size_t)b * d * d;

    float sre = 0.f, sim = 0.f;
    for (int l = 0; l < d; l++) {
        float wr = Wre[i * d + l];
        float wi = Wim[i * d + l];
        float2 g = Gb[l * d + j];
        sre = fmaf(wr, g.x, sre);
        sre = fmaf(-wi, g.y, sre);
        sim = fmaf(wr, g.y, sim);
        sim = fmaf(wi, g.x, sim);
    }

    float mag = sqrtf(sre * sre + sim * sim);
    float tau = fmaxf(expf(log_tau[0]), 1e-8f);
    float scale = tau * sqrtf((float)SSIZE / (float)d);
    float mval = mag / scale;

    __shared__ float red[128];
    red[j] = mval;
    __syncthreads();
    for (int s = d >> 1; s > 0; s >>= 1) {
        if (j < s) red[j] = fmaxf(red[j], red[j + s]);
        __syncthreads();
    }
    float mx = red[0];
    __syncthreads();
    float e = expf(mval - mx);
    red[j] = e;
    __syncthreads();
    for (int s = d >> 1; s > 0; s >>= 1) {
        if (j < s) red[j] += red[j + s];
        __syncthreads();
    }
    float routing = e / red[0];

    float safe = fmaxf(mag, 1e-8f);
    float pre, pim;
    if (mag > 1e-8f) { pre = sre / safe; pim = sim / safe; }
    else             { pre = 1.f;       pim = 0.f; }

    Mout[(size_t)b * d * d + i * d + j] = make_float2(routing * pre, routing * pim);
}

// ---------------- mix: dst(b,i,k) = sum_j M[b,i,j] * u(b,j,k) ----------------
__global__ __launch_bounds__(256)
void mix_kernel(const float* __restrict__ srcR, const float* __restrict__ srcI,
                const float2* __restrict__ M,
                float* __restrict__ dstR, float* __restrict__ dstI,
                int d, int SI, int KL2, int SKL, int SKH)
{
    const int kb0 = blockIdx.x << 6;   // k tile of 64
    const int it  = blockIdx.y << 6;   // i tile of 64
    const int b   = blockIdx.z;
    const int msk = (1 << KL2) - 1;

    __shared__ float2 Ms[KT][66];   // [jj][i]
    __shared__ float2 Us[KT][66];   // [jj][kk]

    const int t  = threadIdx.x;
    const int ti = t & 15, tj = t >> 4;

    float accr[4][4] = {{0}}, acci[4][4] = {{0}};

    const size_t boff = (size_t)b * SSIZE;
    const float2* Mb  = M + (size_t)b * d * d;
    // k tile (64 wide, kb0 % 64 == 0) never straddles a KLO block (KLO >= 64 for all modes)
    const size_t koff = (size_t)(kb0 >> KL2) * SKH + (size_t)(kb0 & msk) * SKL;

    for (int jb = 0; jb < d; jb += KT) {
        // load Ms: 16 jj x 64 i ; l: jj = l&15, ii = l>>4
        #pragma unroll
        for (int iter = 0; iter < 4; iter++) {
            int l  = iter * 256 + t;
            int jj = l & 15;
            int ii = l >> 4;
            Ms[jj][ii] = Mb[(size_t)(it + ii) * d + (jb + jj)];
        }
        // load Us: 16 jj x 64 kk ; l: kk = l&63, jj = l>>6
        #pragma unroll
        for (int iter = 0; iter < 4; iter++) {
            int l  = iter * 256 + t;
            int kk = l & 63;
            int jj = l >> 6;
            size_t off = boff + (size_t)(jb + jj) * SI + koff + (size_t)kk * SKL;
            Us[jj][kk] = make_float2(srcR[off], srcI[off]);
        }
        __syncthreads();
        #pragma unroll
        for (int jj = 0; jj < KT; jj++) {
            float2 m[4], u[4];
            #pragma unroll
            for (int r = 0; r < 4; r++) m[r] = Ms[jj][ti * 4 + r];
            #pragma unroll
            for (int c = 0; c < 4; c++) u[c] = Us[jj][tj * 4 + c];
            #pragma unroll
            for (int r = 0; r < 4; r++)
                #pragma unroll
                for (int c = 0; c < 4; c++) {
                    accr[r][c] = fmaf(m[r].x,  u[c].x, accr[r][c]);
                    accr[r][c] = fmaf(-m[r].y, u[c].y, accr[r][c]);
                    acci[r][c] = fmaf(m[r].x,  u[c].y, acci[r][c]);
                    acci[r][c] = fmaf(m[r].y,  u[c].x, acci[r][c]);
                }
        }
        __syncthreads();
    }

    #pragma unroll
    for (int r = 0; r < 4; r++)
        #pragma unroll
        for (int c = 0; c < 4; c++) {
            int i = it + ti * 4 + r;
            int kc = tj * 4 + c;                       // within the 64-wide k tile
            size_t pos = boff + (size_t)i * SI + koff + (size_t)kc * SKL;
            dstR[pos] = accr[r][c];
            dstI[pos] = acci[r][c];
        }
}

extern "C" void kernel_launch(void* const* d_in, const int* in_sizes, int n_in,
                              void* d_out, int out_size, void* d_ws, size_t ws_size,
                              hipStream_t stream)
{
    const float* xr  = (const float*)d_in[0];
    const float* xi  = (const float*)d_in[1];
    const float* w0r = (const float*)d_in[2];
    const float* w0i = (const float*)d_in[3];
    const float* w1r = (const float*)d_in[4];
    const float* w1i = (const float*)d_in[5];
    const float* w2r = (const float*)d_in[6];
    const float* w2i = (const float*)d_in[7];
    const float* lt  = (const float*)d_in[8];

    float* outR = (float*)d_out;                 // planar real plane
    float* outI = outR + (size_t)BATCH * SSIZE;  // planar imag plane

    // workspace: one planar state buffer + G + M  (~66 MB)
    float*  wsR = (float*)d_ws;
    float*  wsI = wsR + (size_t)BATCH * SSIZE;
    float*  Gf  = wsI + (size_t)BATCH * SSIZE;           // 8*128*128*2 floats
    float2* Mf  = (float2*)(Gf + (size_t)BATCH * 128 * 128 * 2);

    const int nG = BATCH * 128 * 128 * 2;

    // ---------------- mode 0: d=128, SI=8192, KLO=8192 (KL2=13), SKL=1, SKH=0
    zero_kernel<<<dim3((nG + 255) / 256), 256, 0, stream>>>(Gf, nG);
    gram_kernel<<<dim3(4, BATCH, 32), 256, 0, stream>>>(xr, xi, Gf,
                 128, 8192, 13, 1, 0, 256);
    score_kernel<<<dim3(128, BATCH), 128, 0, stream>>>(Gf, w0r, w0i, lt, Mf, 128);
    mix_kernel<<<dim3(128, 2, BATCH), 256, 0, stream>>>(xr, xi, Mf, outR, outI,
                 128, 8192, 13, 1, 0);

    // ---------------- mode 1: d=128, SI=64, KLO=64 (KL2=6), SKL=1, SKH=8192
    zero_kernel<<<dim3((nG + 255) / 256), 256, 0, stream>>>(Gf, nG);
    gram_kernel<<<dim3(4, BATCH, 32), 256, 0, stream>>>(outR, outI, Gf,
                 128, 64, 6, 1, 8192, 256);
    score_kernel<<<dim3(128, BATCH), 128, 0, stream>>>(Gf, w1r, w1i, lt, Mf, 128);
    mix_kernel<<<dim3(128, 2, BATCH), 256, 0, stream>>>(outR, outI, Mf, wsR, wsI,
                 128, 64, 6, 1, 8192);

    // ---------------- mode 2: d=64, SI=1, KLO=128 (KL2=7), SKL=64, SKH=8192
    zero_kernel<<<dim3((nG + 255) / 256), 256, 0, stream>>>(Gf, nG);
    gram_kernel<<<dim3(1, BATCH, 128), 256, 0, stream>>>(wsR, wsI, Gf,
                 64, 1, 7, 64, 8192, 128);
    score_kernel<<<dim3(64, BATCH), 64, 0, stream>>>(Gf, w2r, w2i, lt, Mf, 64);
    mix_kernel<<<dim3(256, 1, BATCH), 256, 0, stream>>>(wsR, wsI, Mf, outR, outI,
                 64, 1, 7, 64, 8192);
}